// Round 6
// baseline (179.401 us; speedup 1.0000x reference)
//
#include <hip/hip_runtime.h>
#include <hip/hip_bf16.h>
#include <math.h>

// DigitCaps routing. PROVEN: P/W/out all FP32; MFMA hi/lo split path correct
// (round 7: PASS absmax 1.95e-3). Round 8: agree -> MFMA, sgemm 512thr.
// Round 9: fused agree (tgemm+reduce_bc, G in LDS), merged split -> 179 us.
// Round 10: cooperative single-kernel -> 449 us REGRESSION (grid.sync kills
//   per-XCD L2 reuse; FETCH 107 MB). Reverted.
// Round 11: sgemm block-ksplit=2 + atomic combine -> 200 us REGRESSION.
// Round 12: sgemm 2 K-streams/wave (2x MLP) -> 184 us NEUTRAL (not in-wave
//   latency bound). Reverted.
// Round 13: XCD-aware sgemm block swizzle -> 178.3 us NEUTRAL-ish (kept; not
//   L2-capacity bound).
// Round 14 (this): sgemm 512 -> 1024 threads (16 waves = 4 waves/SIMD, 18 kk
//   per wave). Probes the last unprobed axis: wave-level TLP. comb[16]
//   epilogue = R12-proven 16-way fp32 sum. Everything else unchanged.
//   P [256][9216] f32, W [1152][10][16][8] f32, out v [256][10][16] f32.

typedef __bf16 bf16x8 __attribute__((ext_vector_type(8)));
typedef float v4f __attribute__((ext_vector_type(4)));

__device__ __forceinline__ float b2f(unsigned short u) {
    return __uint_as_float(((unsigned)u) << 16);
}
__device__ __forceinline__ unsigned short f2b(float f) {   // RNE, finite only
    unsigned x = __float_as_uint(f);
    return (unsigned short)((x + 0x7FFFu + ((x >> 16) & 1u)) >> 16);
}
__device__ __forceinline__ void split4(float4 x, unsigned short* h, unsigned short* l) {
    const float* xf = (const float*)&x;
    #pragma unroll
    for (int i = 0; i < 4; ++i) {
        h[i] = f2b(xf[i]);
        l[i] = f2b(xf[i] - b2f(h[i]));
    }
}
__device__ __forceinline__ uint2 pack4(const unsigned short* s) {
    uint2 w;
    w.x = s[0] | ((unsigned)s[1] << 16);
    w.y = s[2] | ((unsigned)s[3] << 16);
    return w;
}

// ---- merged split: blocks [0,576) split P (64b x 64k tile each);
//      blocks [576,2016) split W elementwise.
__global__ __launch_bounds__(256) void split_pw_kernel(
    const float4* __restrict__ P4, uint2* __restrict__ Ph, uint2* __restrict__ Pl,
    uint4* __restrict__ Pth, uint4* __restrict__ Ptl,
    const float4* __restrict__ W4, uint2* __restrict__ Wh, uint2* __restrict__ Wl)
{
    __shared__ unsigned short ldsH[64 * 72];
    __shared__ unsigned short ldsL[64 * 72];
    const int tid = threadIdx.x;

    if (blockIdx.x >= 576) {   // ---- W path ----
        const int idx = (blockIdx.x - 576) * 256 + tid;    // 0..368639
        unsigned short h[4], l[4];
        split4(W4[idx], h, l);
        Wh[idx] = pack4(h);
        Wl[idx] = pack4(l);
        return;
    }

    // ---- P path ----
    const int b0 = (blockIdx.x & 3) * 64;
    const int k0 = (blockIdx.x >> 2) * 64;
    #pragma unroll
    for (int j = 0; j < 4; ++j) {
        int idx = tid + j * 256;              // 0..1023
        int row = idx >> 4, col4 = idx & 15;  // b-local, k/4-local
        int g = (b0 + row) * 2304 + (k0 >> 2) + col4;
        unsigned short h[4], l[4];
        split4(P4[g], h, l);
        Ph[g] = pack4(h);
        Pl[g] = pack4(l);
        #pragma unroll
        for (int i = 0; i < 4; ++i) {
            ldsH[(col4 * 4 + i) * 72 + row] = h[i];
            ldsL[(col4 * 4 + i) * 72 + row] = l[i];
        }
    }
    __syncthreads();
    #pragma unroll
    for (int j = 0; j < 2; ++j) {
        int idx = tid + j * 256;              // 0..511
        int krow = idx >> 3, bcol = idx & 7;
        unsigned short h[8], l[8];
        #pragma unroll
        for (int i = 0; i < 8; ++i) {
            h[i] = ldsH[krow * 72 + bcol * 8 + i];
            l[i] = ldsL[krow * 72 + bcol * 8 + i];
        }
        uint4 wh, wl;
        wh.x = h[0] | ((unsigned)h[1] << 16); wh.y = h[2] | ((unsigned)h[3] << 16);
        wh.z = h[4] | ((unsigned)h[5] << 16); wh.w = h[6] | ((unsigned)h[7] << 16);
        wl.x = l[0] | ((unsigned)l[1] << 16); wl.y = l[2] | ((unsigned)l[3] << 16);
        wl.z = l[4] | ((unsigned)l[5] << 16); wl.w = l[6] | ((unsigned)l[7] << 16);
        Pth[(size_t)(k0 + krow) * 32 + (b0 >> 3) + bcol] = wh;
        Ptl[(size_t)(k0 + krow) * 32 + (b0 >> 3) + bcol] = wl;
    }
}

// ---- MFMA s-GEMM + fused squash (round-7-proven maps).
// Round 14: 1024 threads = 16 waves (4 waves/SIMD), 18 kk per wave.
// XCD-aware block->tile swizzle kept from round 13 (bijective over 160).
// Writes v transposed hi/lo (vt[cd][b]) for agree A; last iter writes outb.
__global__ __launch_bounds__(1024) void sgemm_kernel(
    const uint4* __restrict__ Ah, const uint4* __restrict__ Al,
    const uint4* __restrict__ Bh, const uint4* __restrict__ Bl,
    uint2* __restrict__ vth, uint2* __restrict__ vtl,
    float* __restrict__ outb, int uniform, int last)
{
    __shared__ float comb[16][64][4];
    const int tid = threadIdx.x;
    const int wave = tid >> 6, lane = tid & 63;   // wave in [0,16)
    const int lm = lane & 15, q = lane >> 4;
    const int xcd = blockIdx.x & 7, s0 = blockIdx.x >> 3;
    const int c = (xcd & 1) * 5 + (s0 % 5);
    const int b0 = ((xcd >> 1) * 4 + (s0 / 5)) * 16;

    const uint4* Ahp = Ah + (size_t)(b0 + lm) * 1152 + q;
    const uint4* Alp = Al + (size_t)(b0 + lm) * 1152 + q;
    const uint4* Bhp = Bh + ((size_t)q * 10 + c) * 16 + lm;
    const uint4* Blp = Bl + ((size_t)q * 10 + c) * 16 + lm;

    v4f acc = {0.f, 0.f, 0.f, 0.f};
    const int kk0 = wave * 18;                    // 16 waves x 18 kk = 288
    for (int kk = kk0; kk < kk0 + 18; ++kk) {
        bf16x8 ah = __builtin_bit_cast(bf16x8, Ahp[(size_t)kk * 4]);
        bf16x8 al = __builtin_bit_cast(bf16x8, Alp[(size_t)kk * 4]);
        bf16x8 bh = __builtin_bit_cast(bf16x8, Bhp[(size_t)kk * 640]);
        bf16x8 bl = __builtin_bit_cast(bf16x8, Blp[(size_t)kk * 640]);
        acc = __builtin_amdgcn_mfma_f32_16x16x32_bf16(ah, bh, acc, 0, 0, 0);
        acc = __builtin_amdgcn_mfma_f32_16x16x32_bf16(ah, bl, acc, 0, 0, 0);
        acc = __builtin_amdgcn_mfma_f32_16x16x32_bf16(al, bh, acc, 0, 0, 0);
    }
    #pragma unroll
    for (int r = 0; r < 4; ++r) comb[wave][lane][r] = acc[r];
    __syncthreads();
    if (wave == 0) {
        float s[4], sq[4];
        #pragma unroll
        for (int r = 0; r < 4; ++r) {
            s[r] = 0.f;
            #pragma unroll
            for (int w = 0; w < 16; ++w) s[r] += comb[w][lane][r];
            if (uniform) s[r] *= 0.1f;
            sq[r] = s[r] * s[r];
        }
        #pragma unroll
        for (int m = 1; m < 16; m <<= 1) {
            #pragma unroll
            for (int r = 0; r < 4; ++r) sq[r] += __shfl_xor(sq[r], m);
        }
        float v[4];
        #pragma unroll
        for (int r = 0; r < 4; ++r) {
            const float n = sq[r];
            v[r] = s[r] * sqrtf(n) / (1.0f + n);
        }
        if (!last) {
            unsigned short h[4], l[4];
            #pragma unroll
            for (int r = 0; r < 4; ++r) {
                h[r] = f2b(v[r]);
                l[r] = f2b(v[r] - b2f(h[r]));
            }
            const int o = (c * 16 + lm) * 64 + (b0 >> 2) + q;   // uint2 units
            vth[o] = pack4(h);
            vtl[o] = pack4(l);
        } else {
            #pragma unroll
            for (int r = 0; r < 4; ++r)
                outb[((b0 + q * 4 + r) * 10 + c) * 16 + lm] = v[r];
        }
    }
}

// ---- agree: fused tgemm + reduce_bc (round-9-proven). One block per 16-ri
// tile (n0 = bid*16, covering r = 2*bid, 2*bid+1). 4 waves split K=256 ->
// 2 kk-steps each; partials summed via LDS; G kept in LDS; then reduce_bc
// runs on the two r-rows with 128 threads each; emits Bc hi/lo + b_log.
__global__ __launch_bounds__(256) void agree_kernel(
    const uint4* __restrict__ vth, const uint4* __restrict__ vtl,
    const uint4* __restrict__ Pth, const uint4* __restrict__ Ptl,
    const float* __restrict__ Wf, float* __restrict__ b_log,
    unsigned short* __restrict__ Bh, unsigned short* __restrict__ Bl, int first)
{
    __shared__ float comb2[40][4][64];   // [mt*4+reg][wave][lane] - conflict-free
    __shared__ float G_lds[160][18];     // [cd][ri-local], pad 16->18
    __shared__ float part[4][10];
    __shared__ float cl[2][10];
    const int tid = threadIdx.x;
    const int wave = tid >> 6, lane = tid & 63;
    const int lm = lane & 15, q = lane >> 4;
    const int n0 = blockIdx.x * 16;

    // ---- K-split tgemm: wave handles kk in {2*wave, 2*wave+1} ----
    v4f acc[10];
    #pragma unroll
    for (int mt = 0; mt < 10; ++mt) acc[mt] = (v4f){0.f, 0.f, 0.f, 0.f};
    #pragma unroll
    for (int kx = 0; kx < 2; ++kx) {
        const int kk = wave * 2 + kx;
        bf16x8 bh_ = __builtin_bit_cast(bf16x8, Pth[(size_t)(n0 + lm) * 32 + kk * 4 + q]);
        bf16x8 bl_ = __builtin_bit_cast(bf16x8, Ptl[(size_t)(n0 + lm) * 32 + kk * 4 + q]);
        #pragma unroll
        for (int mt = 0; mt < 10; ++mt) {
            bf16x8 ah = __builtin_bit_cast(bf16x8, vth[(size_t)(mt * 16 + lm) * 32 + kk * 4 + q]);
            bf16x8 al = __builtin_bit_cast(bf16x8, vtl[(size_t)(mt * 16 + lm) * 32 + kk * 4 + q]);
            acc[mt] = __builtin_amdgcn_mfma_f32_16x16x32_bf16(ah, bh_, acc[mt], 0, 0, 0);
            acc[mt] = __builtin_amdgcn_mfma_f32_16x16x32_bf16(ah, bl_, acc[mt], 0, 0, 0);
            acc[mt] = __builtin_amdgcn_mfma_f32_16x16x32_bf16(al, bh_, acc[mt], 0, 0, 0);
        }
    }
    #pragma unroll
    for (int mt = 0; mt < 10; ++mt)
        #pragma unroll
        for (int r = 0; r < 4; ++r)
            comb2[mt * 4 + r][wave][lane] = acc[mt][r];
    __syncthreads();
    // ---- sum wave partials -> G_lds. Wave w owns c40 = w*10 .. w*10+9 ----
    #pragma unroll
    for (int j = 0; j < 10; ++j) {
        const int c40 = wave * 10 + j;
        float s_ = comb2[c40][0][lane] + comb2[c40][1][lane]
                 + comb2[c40][2][lane] + comb2[c40][3][lane];
        const int mt = c40 >> 2, reg = c40 & 3;
        G_lds[mt * 16 + q * 4 + reg][lm] = s_;     // G[cd][ri = n0+lm]
    }
    __syncthreads();

    // ---- reduce_bc phase (proven logic; 128 threads per r-row) ----
    const int rl = tid >> 7;        // 0..1 -> which r this half-block owns
    const int t = tid & 127;        // d*8+i
    const int r = (n0 >> 3) + rl;
    const int wid2 = tid >> 6;      // 0..3

    float wv[10], a[10];
    #pragma unroll
    for (int c = 0; c < 10; ++c) {
        wv[c] = Wf[((size_t)r * 10 + c) * 128 + t];
        float g = G_lds[c * 16 + (t >> 3)][rl * 8 + (t & 7)];
        a[c] = wv[c] * g;
    }
    #pragma unroll
    for (int m = 1; m < 64; m <<= 1) {
        #pragma unroll
        for (int c = 0; c < 10; ++c) a[c] += __shfl_xor(a[c], m);
    }
    if (lane == 0) {
        #pragma unroll
        for (int c = 0; c < 10; ++c) part[wid2][c] = a[c];
    }
    __syncthreads();
    if (t < 10) {    // threads 0..9 (rl=0) and 128..137 (rl=1)
        float s_ = (part[rl * 2][t] + part[rl * 2 + 1][t]) * (1.0f / 256.0f);
        float bn = (first ? 0.f : b_log[r * 10 + t]) + s_;
        b_log[r * 10 + t] = bn;
        part[rl * 2][t] = bn;            // reuse as softmax scratch
    }
    __syncthreads();
    if (t < 10) {
        float mx = part[rl * 2][0];
        #pragma unroll
        for (int j = 1; j < 10; ++j) mx = fmaxf(mx, part[rl * 2][j]);
        float den = 0.f;
        #pragma unroll
        for (int j = 0; j < 10; ++j) den += __expf(part[rl * 2][j] - mx);
        cl[rl][t] = __expf(part[rl * 2][t] - mx) / den;
    }
    __syncthreads();
    #pragma unroll
    for (int c = 0; c < 10; ++c) {
        float x = cl[rl][c] * wv[c];
        unsigned short h = f2b(x);
        Bh[((size_t)r * 10 + c) * 128 + t] = h;
        Bl[((size_t)r * 10 + c) * 128 + t] = f2b(x - b2f(h));
    }
}

extern "C" void kernel_launch(void* const* d_in, const int* in_sizes, int n_in,
                              void* d_out, int out_size, void* d_ws, size_t ws_size,
                              hipStream_t stream)
{
    const float4* P4 = (const float4*)d_in[0];
    const float4* W4 = (const float4*)d_in[1];
    char* wsb = (char*)d_ws;
    // BYTE offsets (audited, all 16B-aligned):
    float* b_log = (float*)(wsb + 0);              // 46080 B
    uint2* vth   = (uint2*)(wsb + 131072);         // 81920 B
    uint2* vtl   = (uint2*)(wsb + 262144);         // 81920 B
    uint2* Ph    = (uint2*)(wsb + 393216);         // 4718592 B
    uint2* Pl    = (uint2*)(wsb + 5242880);        // 4718592 B
    uint4* Pth   = (uint4*)(wsb + 10485760);       // 4718592 B
    uint4* Ptl   = (uint4*)(wsb + 15728640);       // 4718592 B
    uint2* Wh    = (uint2*)(wsb + 20971520);       // 2949120 B
    uint2* Wl    = (uint2*)(wsb + 25165824);       // 2949120 B
    unsigned short* Bh = (unsigned short*)(wsb + 29360128);  // 2949120 B
    unsigned short* Bl = (unsigned short*)(wsb + 33554432);  // 2949120 B
    float* outb  = (float*)d_out;
    const float* Wf = (const float*)W4;

    split_pw_kernel<<<2016, 256, 0, stream>>>(P4, Ph, Pl, Pth, Ptl, W4, Wh, Wl);

    // iter 0: B = W, uniform c = 0.1 post-MFMA
    sgemm_kernel<<<160, 1024, 0, stream>>>((const uint4*)Ph, (const uint4*)Pl,
                                           (const uint4*)Wh, (const uint4*)Wl,
                                           vth, vtl, outb, 1, 0);
    agree_kernel<<<576, 256, 0, stream>>>((const uint4*)vth, (const uint4*)vtl,
                                          Pth, Ptl, Wf, b_log, Bh, Bl, 1);
    // iter 1
    sgemm_kernel<<<160, 1024, 0, stream>>>((const uint4*)Ph, (const uint4*)Pl,
                                           (const uint4*)Bh, (const uint4*)Bl,
                                           vth, vtl, outb, 0, 0);
    agree_kernel<<<576, 256, 0, stream>>>((const uint4*)vth, (const uint4*)vtl,
                                          Pth, Ptl, Wf, b_log, Bh, Bl, 0);
    // iter 2 -> d_out
    sgemm_kernel<<<160, 1024, 0, stream>>>((const uint4*)Ph, (const uint4*)Pl,
                                           (const uint4*)Bh, (const uint4*)Bl,
                                           vth, vtl, outb, 0, 1);
}

// Round 7
// 160.537 us; speedup vs baseline: 1.1175x; 1.1175x over previous
//
#include <hip/hip_runtime.h>
#include <hip/hip_bf16.h>
#include <math.h>

// DigitCaps routing. PROVEN: P/W/out all FP32; MFMA hi/lo split path correct
// (round 7: PASS absmax 1.95e-3). Round 8: agree -> MFMA, sgemm 512thr.
// Round 9: fused agree (tgemm+reduce_bc, G in LDS), merged split -> 179 us.
// Round 10: cooperative single-kernel -> 449 us REGRESSION (grid.sync kills
//   per-XCD L2 reuse). Round 11: block-ksplit+atomics -> 200 us REGRESSION.
// Round 12: 2 K-streams/wave (MLP) -> 184 NEUTRAL. Round 13: XCD swizzle ->
//   178.3 kept. Round 14: 16 waves (TLP) -> 179.4 NEUTRAL.
// Ledger: sgemm is not latency/parallelism/locality bound -> issue-rate bound
//   on 16-segment A-gathers (lm stride 18KB).
// Round 15 (this): fragment-ready A layout. split_p emits PA[bt][kk][lane]
//   (uint4 = exact MFMA A-fragment) instead of row-major Ph/Pl; sgemm A-load
//   becomes 64x16B contiguous. Bit-identical values, ~4x fewer VMEM segments.
//   P [256][9216] f32, W [1152][10][16][8] f32, out v [256][10][16] f32.

typedef __bf16 bf16x8 __attribute__((ext_vector_type(8)));
typedef float v4f __attribute__((ext_vector_type(4)));

__device__ __forceinline__ float b2f(unsigned short u) {
    return __uint_as_float(((unsigned)u) << 16);
}
__device__ __forceinline__ unsigned short f2b(float f) {   // RNE, finite only
    unsigned x = __float_as_uint(f);
    return (unsigned short)((x + 0x7FFFu + ((x >> 16) & 1u)) >> 16);
}
__device__ __forceinline__ void split4(float4 x, unsigned short* h, unsigned short* l) {
    const float* xf = (const float*)&x;
    #pragma unroll
    for (int i = 0; i < 4; ++i) {
        h[i] = f2b(xf[i]);
        l[i] = f2b(xf[i] - b2f(h[i]));
    }
}
__device__ __forceinline__ uint2 pack4(const unsigned short* s) {
    uint2 w;
    w.x = s[0] | ((unsigned)s[1] << 16);
    w.y = s[2] | ((unsigned)s[3] << 16);
    return w;
}
__device__ __forceinline__ uint4 pack8(const unsigned short* s) {
    uint4 w;
    w.x = s[0] | ((unsigned)s[1] << 16); w.y = s[2] | ((unsigned)s[3] << 16);
    w.z = s[4] | ((unsigned)s[5] << 16); w.w = s[6] | ((unsigned)s[7] << 16);
    return w;
}

// ---- merged split: blocks [0,576) split P (64b x 64k tile each);
//      blocks [576,2016) split W elementwise.
// P-path emits: PA[bt=16][kk=288][lane=64] uint4 fragment-major (hi/lo) for
// sgemm A, and Pt[k][b] transposed (hi/lo) for agree B.
__global__ __launch_bounds__(256) void split_pw_kernel(
    const float4* __restrict__ P4, uint4* __restrict__ PAh, uint4* __restrict__ PAl,
    uint4* __restrict__ Pth, uint4* __restrict__ Ptl,
    const float4* __restrict__ W4, uint2* __restrict__ Wh, uint2* __restrict__ Wl)
{
    __shared__ unsigned short ldsH[64 * 72];
    __shared__ unsigned short ldsL[64 * 72];
    const int tid = threadIdx.x;

    if (blockIdx.x >= 576) {   // ---- W path ----
        const int idx = (blockIdx.x - 576) * 256 + tid;    // 0..368639
        unsigned short h[4], l[4];
        split4(W4[idx], h, l);
        Wh[idx] = pack4(h);
        Wl[idx] = pack4(l);
        return;
    }

    // ---- P path: stage hi/lo planes transposed in LDS ----
    const int b0 = (blockIdx.x & 3) * 64;
    const int k0 = (blockIdx.x >> 2) * 64;
    #pragma unroll
    for (int j = 0; j < 4; ++j) {
        int idx = tid + j * 256;              // 0..1023
        int row = idx >> 4, col4 = idx & 15;  // b-local, k/4-local
        int g = (b0 + row) * 2304 + (k0 >> 2) + col4;
        unsigned short h[4], l[4];
        split4(P4[g], h, l);
        #pragma unroll
        for (int i = 0; i < 4; ++i) {
            ldsH[(col4 * 4 + i) * 72 + row] = h[i];   // [k-local][b-local]
            ldsL[(col4 * 4 + i) * 72 + row] = l[i];
        }
    }
    __syncthreads();
    // ---- pass A: fragment-major PA for sgemm (replaces row-major Ph/Pl).
    // item: (bt 0..3, kkl 0..1, lane 0..63); lane=(lm,q); uint4 = 8 bf16 at
    // P[b0+bt*16+lm][k0 + kkl*32 + q*8 .. +7].
    #pragma unroll
    for (int j = 0; j < 2; ++j) {
        int idx = tid + j * 256;              // 0..511
        int lane = idx & 63, sub = idx >> 6;  // sub 0..7
        int bt = sub & 3, kkl = sub >> 1 >> 1; // sub>>2
        int lm = lane & 15, q = lane >> 4;
        unsigned short h[8], l[8];
        #pragma unroll
        for (int t = 0; t < 8; ++t) {
            int kl = kkl * 32 + q * 8 + t;
            int row = bt * 16 + lm;
            h[t] = ldsH[kl * 72 + row];
            l[t] = ldsL[kl * 72 + row];
        }
        size_t o = ((size_t)((blockIdx.x & 3) * 4 + bt) * 288
                    + ((blockIdx.x >> 2) * 2 + kkl)) * 64 + lane;
        PAh[o] = pack8(h);
        PAl[o] = pack8(l);
    }
    // ---- pass B: transposed Pt[k][b] for agree (unchanged, proven) ----
    #pragma unroll
    for (int j = 0; j < 2; ++j) {
        int idx = tid + j * 256;              // 0..511
        int krow = idx >> 3, bcol = idx & 7;
        unsigned short h[8], l[8];
        #pragma unroll
        for (int i = 0; i < 8; ++i) {
            h[i] = ldsH[krow * 72 + bcol * 8 + i];
            l[i] = ldsL[krow * 72 + bcol * 8 + i];
        }
        Pth[(size_t)(k0 + krow) * 32 + (b0 >> 3) + bcol] = pack8(h);
        Ptl[(size_t)(k0 + krow) * 32 + (b0 >> 3) + bcol] = pack8(l);
    }
}

// ---- MFMA s-GEMM + fused squash (round-7-proven maps; 512 thr, K/8 per wave).
// Round 15: A from fragment-major PA -> per-kk A-load is 64x16B contiguous.
// XCD-aware block->tile swizzle kept (bijective over 160 blocks).
// Writes v transposed hi/lo (vt[cd][b]) for agree A; last iter writes outb.
__global__ __launch_bounds__(512) void sgemm_kernel(
    const uint4* __restrict__ Ah, const uint4* __restrict__ Al,
    const uint4* __restrict__ Bh, const uint4* __restrict__ Bl,
    uint2* __restrict__ vth, uint2* __restrict__ vtl,
    float* __restrict__ outb, int uniform, int last)
{
    __shared__ float comb[8][64][4];
    const int tid = threadIdx.x;
    const int wave = tid >> 6, lane = tid & 63;
    const int lm = lane & 15, q = lane >> 4;
    const int xcd = blockIdx.x & 7, s0 = blockIdx.x >> 3;
    const int c = (xcd & 1) * 5 + (s0 % 5);
    const int b0 = ((xcd >> 1) * 4 + (s0 / 5)) * 16;

    const uint4* Ahp = Ah + (size_t)(b0 >> 4) * 288 * 64 + lane;
    const uint4* Alp = Al + (size_t)(b0 >> 4) * 288 * 64 + lane;
    const uint4* Bhp = Bh + ((size_t)q * 10 + c) * 16 + lm;
    const uint4* Blp = Bl + ((size_t)q * 10 + c) * 16 + lm;

    v4f acc = {0.f, 0.f, 0.f, 0.f};
    const int kk0 = wave * 36;
    for (int kk = kk0; kk < kk0 + 36; ++kk) {
        bf16x8 ah = __builtin_bit_cast(bf16x8, Ahp[(size_t)kk * 64]);
        bf16x8 al = __builtin_bit_cast(bf16x8, Alp[(size_t)kk * 64]);
        bf16x8 bh = __builtin_bit_cast(bf16x8, Bhp[(size_t)kk * 640]);
        bf16x8 bl = __builtin_bit_cast(bf16x8, Blp[(size_t)kk * 640]);
        acc = __builtin_amdgcn_mfma_f32_16x16x32_bf16(ah, bh, acc, 0, 0, 0);
        acc = __builtin_amdgcn_mfma_f32_16x16x32_bf16(ah, bl, acc, 0, 0, 0);
        acc = __builtin_amdgcn_mfma_f32_16x16x32_bf16(al, bh, acc, 0, 0, 0);
    }
    #pragma unroll
    for (int r = 0; r < 4; ++r) comb[wave][lane][r] = acc[r];
    __syncthreads();
    if (wave == 0) {
        float s[4], sq[4];
        #pragma unroll
        for (int r = 0; r < 4; ++r) {
            s[r] = 0.f;
            #pragma unroll
            for (int w = 0; w < 8; ++w) s[r] += comb[w][lane][r];
            if (uniform) s[r] *= 0.1f;
            sq[r] = s[r] * s[r];
        }
        #pragma unroll
        for (int m = 1; m < 16; m <<= 1) {
            #pragma unroll
            for (int r = 0; r < 4; ++r) sq[r] += __shfl_xor(sq[r], m);
        }
        float v[4];
        #pragma unroll
        for (int r = 0; r < 4; ++r) {
            const float n = sq[r];
            v[r] = s[r] * sqrtf(n) / (1.0f + n);
        }
        if (!last) {
            unsigned short h[4], l[4];
            #pragma unroll
            for (int r = 0; r < 4; ++r) {
                h[r] = f2b(v[r]);
                l[r] = f2b(v[r] - b2f(h[r]));
            }
            const int o = (c * 16 + lm) * 64 + (b0 >> 2) + q;   // uint2 units
            vth[o] = pack4(h);
            vtl[o] = pack4(l);
        } else {
            #pragma unroll
            for (int r = 0; r < 4; ++r)
                outb[((b0 + q * 4 + r) * 10 + c) * 16 + lm] = v[r];
        }
    }
}

// ---- agree: fused tgemm + reduce_bc (round-9-proven). One block per 16-ri
// tile (n0 = bid*16, covering r = 2*bid, 2*bid+1). 4 waves split K=256 ->
// 2 kk-steps each; partials summed via LDS; G kept in LDS; then reduce_bc
// runs on the two r-rows with 128 threads each; emits Bc hi/lo + b_log.
__global__ __launch_bounds__(256) void agree_kernel(
    const uint4* __restrict__ vth, const uint4* __restrict__ vtl,
    const uint4* __restrict__ Pth, const uint4* __restrict__ Ptl,
    const float* __restrict__ Wf, float* __restrict__ b_log,
    unsigned short* __restrict__ Bh, unsigned short* __restrict__ Bl, int first)
{
    __shared__ float comb2[40][4][64];   // [mt*4+reg][wave][lane] - conflict-free
    __shared__ float G_lds[160][18];     // [cd][ri-local], pad 16->18
    __shared__ float part[4][10];
    __shared__ float cl[2][10];
    const int tid = threadIdx.x;
    const int wave = tid >> 6, lane = tid & 63;
    const int lm = lane & 15, q = lane >> 4;
    const int n0 = blockIdx.x * 16;

    // ---- K-split tgemm: wave handles kk in {2*wave, 2*wave+1} ----
    v4f acc[10];
    #pragma unroll
    for (int mt = 0; mt < 10; ++mt) acc[mt] = (v4f){0.f, 0.f, 0.f, 0.f};
    #pragma unroll
    for (int kx = 0; kx < 2; ++kx) {
        const int kk = wave * 2 + kx;
        bf16x8 bh_ = __builtin_bit_cast(bf16x8, Pth[(size_t)(n0 + lm) * 32 + kk * 4 + q]);
        bf16x8 bl_ = __builtin_bit_cast(bf16x8, Ptl[(size_t)(n0 + lm) * 32 + kk * 4 + q]);
        #pragma unroll
        for (int mt = 0; mt < 10; ++mt) {
            bf16x8 ah = __builtin_bit_cast(bf16x8, vth[(size_t)(mt * 16 + lm) * 32 + kk * 4 + q]);
            bf16x8 al = __builtin_bit_cast(bf16x8, vtl[(size_t)(mt * 16 + lm) * 32 + kk * 4 + q]);
            acc[mt] = __builtin_amdgcn_mfma_f32_16x16x32_bf16(ah, bh_, acc[mt], 0, 0, 0);
            acc[mt] = __builtin_amdgcn_mfma_f32_16x16x32_bf16(ah, bl_, acc[mt], 0, 0, 0);
            acc[mt] = __builtin_amdgcn_mfma_f32_16x16x32_bf16(al, bh_, acc[mt], 0, 0, 0);
        }
    }
    #pragma unroll
    for (int mt = 0; mt < 10; ++mt)
        #pragma unroll
        for (int r = 0; r < 4; ++r)
            comb2[mt * 4 + r][wave][lane] = acc[mt][r];
    __syncthreads();
    // ---- sum wave partials -> G_lds. Wave w owns c40 = w*10 .. w*10+9 ----
    #pragma unroll
    for (int j = 0; j < 10; ++j) {
        const int c40 = wave * 10 + j;
        float s_ = comb2[c40][0][lane] + comb2[c40][1][lane]
                 + comb2[c40][2][lane] + comb2[c40][3][lane];
        const int mt = c40 >> 2, reg = c40 & 3;
        G_lds[mt * 16 + q * 4 + reg][lm] = s_;     // G[cd][ri = n0+lm]
    }
    __syncthreads();

    // ---- reduce_bc phase (proven logic; 128 threads per r-row) ----
    const int rl = tid >> 7;        // 0..1 -> which r this half-block owns
    const int t = tid & 127;        // d*8+i
    const int r = (n0 >> 3) + rl;
    const int wid2 = tid >> 6;      // 0..3

    float wv[10], a[10];
    #pragma unroll
    for (int c = 0; c < 10; ++c) {
        wv[c] = Wf[((size_t)r * 10 + c) * 128 + t];
        float g = G_lds[c * 16 + (t >> 3)][rl * 8 + (t & 7)];
        a[c] = wv[c] * g;
    }
    #pragma unroll
    for (int m = 1; m < 64; m <<= 1) {
        #pragma unroll
        for (int c = 0; c < 10; ++c) a[c] += __shfl_xor(a[c], m);
    }
    if (lane == 0) {
        #pragma unroll
        for (int c = 0; c < 10; ++c) part[wid2][c] = a[c];
    }
    __syncthreads();
    if (t < 10) {    // threads 0..9 (rl=0) and 128..137 (rl=1)
        float s_ = (part[rl * 2][t] + part[rl * 2 + 1][t]) * (1.0f / 256.0f);
        float bn = (first ? 0.f : b_log[r * 10 + t]) + s_;
        b_log[r * 10 + t] = bn;
        part[rl * 2][t] = bn;            // reuse as softmax scratch
    }
    __syncthreads();
    if (t < 10) {
        float mx = part[rl * 2][0];
        #pragma unroll
        for (int j = 1; j < 10; ++j) mx = fmaxf(mx, part[rl * 2][j]);
        float den = 0.f;
        #pragma unroll
        for (int j = 0; j < 10; ++j) den += __expf(part[rl * 2][j] - mx);
        cl[rl][t] = __expf(part[rl * 2][t] - mx) / den;
    }
    __syncthreads();
    #pragma unroll
    for (int c = 0; c < 10; ++c) {
        float x = cl[rl][c] * wv[c];
        unsigned short h = f2b(x);
        Bh[((size_t)r * 10 + c) * 128 + t] = h;
        Bl[((size_t)r * 10 + c) * 128 + t] = f2b(x - b2f(h));
    }
}

extern "C" void kernel_launch(void* const* d_in, const int* in_sizes, int n_in,
                              void* d_out, int out_size, void* d_ws, size_t ws_size,
                              hipStream_t stream)
{
    const float4* P4 = (const float4*)d_in[0];
    const float4* W4 = (const float4*)d_in[1];
    char* wsb = (char*)d_ws;
    // BYTE offsets (audited, all 16B-aligned):
    float* b_log = (float*)(wsb + 0);              // 46080 B
    uint2* vth   = (uint2*)(wsb + 131072);         // 81920 B
    uint2* vtl   = (uint2*)(wsb + 262144);         // 81920 B
    uint4* PAh   = (uint4*)(wsb + 393216);         // 4718592 B (16*288*64*16)
    uint4* PAl   = (uint4*)(wsb + 5242880);        // 4718592 B
    uint4* Pth   = (uint4*)(wsb + 10485760);       // 4718592 B
    uint4* Ptl   = (uint4*)(wsb + 15728640);       // 4718592 B
    uint2* Wh    = (uint2*)(wsb + 20971520);       // 2949120 B
    uint2* Wl    = (uint2*)(wsb + 25165824);       // 2949120 B
    unsigned short* Bh = (unsigned short*)(wsb + 29360128);  // 2949120 B
    unsigned short* Bl = (unsigned short*)(wsb + 33554432);  // 2949120 B
    float* outb  = (float*)d_out;
    const float* Wf = (const float*)W4;

    split_pw_kernel<<<2016, 256, 0, stream>>>(P4, PAh, PAl, Pth, Ptl, W4, Wh, Wl);

    // iter 0: B = W, uniform c = 0.1 post-MFMA
    sgemm_kernel<<<160, 512, 0, stream>>>((const uint4*)PAh, (const uint4*)PAl,
                                          (const uint4*)Wh, (const uint4*)Wl,
                                          vth, vtl, outb, 1, 0);
    agree_kernel<<<576, 256, 0, stream>>>((const uint4*)vth, (const uint4*)vtl,
                                          Pth, Ptl, Wf, b_log, Bh, Bl, 1);
    // iter 1
    sgemm_kernel<<<160, 512, 0, stream>>>((const uint4*)PAh, (const uint4*)PAl,
                                          (const uint4*)Bh, (const uint4*)Bl,
                                          vth, vtl, outb, 0, 0);
    agree_kernel<<<576, 256, 0, stream>>>((const uint4*)vth, (const uint4*)vtl,
                                          Pth, Ptl, Wf, b_log, Bh, Bl, 0);
    // iter 2 -> d_out
    sgemm_kernel<<<160, 512, 0, stream>>>((const uint4*)PAh, (const uint4*)PAl,
                                          (const uint4*)Bh, (const uint4*)Bl,
                                          vth, vtl, outb, 0, 1);
}

// Round 8
// 136.508 us; speedup vs baseline: 1.3142x; 1.1760x over previous
//
#include <hip/hip_runtime.h>
#include <hip/hip_bf16.h>
#include <math.h>

// DigitCaps routing. PROVEN: P/W/out all FP32; MFMA hi/lo split path correct
// (round 7: PASS absmax 1.95e-3). Round 9: fused agree + merged split -> 179.
// Round 10: cooperative -> 449 REGRESSION. Round 11: block-ksplit -> 200
// REGRESSION. Round 12: MLP -> 184 NEUTRAL. Round 13: XCD swizzle -> 178 kept.
// Round 14: TLP -> 179 NEUTRAL. Round 15: fragment-major A (PA[bt][kk][lane])
//   -> 160.5 us WIN: sgemm was VMEM segment-issue bound (16-seg gathers).
// Round 16 (this): scale the confirmed mechanism to ALL remaining scattered
//   streams: W/Bc -> WF[c][kk][lane] (sgemm B 4-seg -> 1-seg), Pt ->
//   PT[tile][kk][lane], vt -> VT[mt][kk][lane] (agree 16-seg -> 1-seg; 44
//   such loads/block x 1152 blocks). Bit-identical values, address remaps only.
//   P [256][9216] f32, W [1152][10][16][8] f32, out v [256][10][16] f32.

typedef __bf16 bf16x8 __attribute__((ext_vector_type(8)));
typedef float v4f __attribute__((ext_vector_type(4)));

__device__ __forceinline__ float b2f(unsigned short u) {
    return __uint_as_float(((unsigned)u) << 16);
}
__device__ __forceinline__ unsigned short f2b(float f) {   // RNE, finite only
    unsigned x = __float_as_uint(f);
    return (unsigned short)((x + 0x7FFFu + ((x >> 16) & 1u)) >> 16);
}
__device__ __forceinline__ void split4(float4 x, unsigned short* h, unsigned short* l) {
    const float* xf = (const float*)&x;
    #pragma unroll
    for (int i = 0; i < 4; ++i) {
        h[i] = f2b(xf[i]);
        l[i] = f2b(xf[i] - b2f(h[i]));
    }
}
__device__ __forceinline__ uint2 pack4(const unsigned short* s) {
    uint2 w;
    w.x = s[0] | ((unsigned)s[1] << 16);
    w.y = s[2] | ((unsigned)s[3] << 16);
    return w;
}
__device__ __forceinline__ uint4 pack8(const unsigned short* s) {
    uint4 w;
    w.x = s[0] | ((unsigned)s[1] << 16); w.y = s[2] | ((unsigned)s[3] << 16);
    w.z = s[4] | ((unsigned)s[5] << 16); w.w = s[6] | ((unsigned)s[7] << 16);
    return w;
}

// ---- merged split: blocks [0,576) split P; blocks [576,2016) split W.
// Emits (all fragment-major, lane-contiguous for their consumers):
//   PA[bt=16][kk=288][lane=64]   uint4 hi/lo  (sgemm A)
//   PT[tile=576][kk=8][lane=64]  uint4 hi/lo  (agree B)
//   WF[c=10][kk=288][lane=64]    as uint2 pairs (sgemm B, iter 0)
__global__ __launch_bounds__(256) void split_pw_kernel(
    const float4* __restrict__ P4, uint4* __restrict__ PAh, uint4* __restrict__ PAl,
    uint4* __restrict__ PTh, uint4* __restrict__ PTl,
    const float4* __restrict__ W4, uint2* __restrict__ Wh, uint2* __restrict__ Wl)
{
    __shared__ unsigned short ldsH[64 * 72];
    __shared__ unsigned short ldsL[64 * 72];
    const int tid = threadIdx.x;

    if (blockIdx.x >= 576) {   // ---- W path: fragment-major remap ----
        const int idx = (blockIdx.x - 576) * 256 + tid;    // float4 idx 0..368639
        const int j = idx & 1;
        const int t16 = idx >> 1;          // (r*10+c)*16 + d
        const int d = t16 & 15;
        const int rc = t16 >> 4;           // r*10 + c
        const int cc = rc % 10, r = rc / 10;
        unsigned short h[4], l[4];
        split4(W4[idx], h, l);
        const size_t f = ((size_t)cc * 288 + (r >> 2)) * 64 + (r & 3) * 16 + d;
        Wh[f * 2 + j] = pack4(h);
        Wl[f * 2 + j] = pack4(l);
        return;
    }

    // ---- P path: stage hi/lo planes transposed in LDS ----
    const int b0 = (blockIdx.x & 3) * 64;
    const int k0 = (blockIdx.x >> 2) * 64;
    #pragma unroll
    for (int j = 0; j < 4; ++j) {
        int idx = tid + j * 256;              // 0..1023
        int row = idx >> 4, col4 = idx & 15;  // b-local, k/4-local
        int g = (b0 + row) * 2304 + (k0 >> 2) + col4;
        unsigned short h[4], l[4];
        split4(P4[g], h, l);
        #pragma unroll
        for (int i = 0; i < 4; ++i) {
            ldsH[(col4 * 4 + i) * 72 + row] = h[i];   // [k-local][b-local]
            ldsL[(col4 * 4 + i) * 72 + row] = l[i];
        }
    }
    __syncthreads();
    // ---- pass A: fragment-major PA for sgemm (R15-proven) ----
    #pragma unroll
    for (int j = 0; j < 2; ++j) {
        int idx = tid + j * 256;              // 0..511
        int lane = idx & 63, sub = idx >> 6;  // sub 0..7
        int bt = sub & 3, kkl = sub >> 2;     // 0..1
        int lm = lane & 15, q = lane >> 4;
        unsigned short h[8], l[8];
        #pragma unroll
        for (int t = 0; t < 8; ++t) {
            int kl = kkl * 32 + q * 8 + t;
            int row = bt * 16 + lm;
            h[t] = ldsH[kl * 72 + row];
            l[t] = ldsL[kl * 72 + row];
        }
        size_t o = ((size_t)((blockIdx.x & 3) * 4 + bt) * 288
                    + ((blockIdx.x >> 2) * 2 + kkl)) * 64 + lane;
        PAh[o] = pack8(h);
        PAl[o] = pack8(l);
    }
    // ---- pass B: fragment-major PT for agree (same gather, new address) ----
    #pragma unroll
    for (int j = 0; j < 2; ++j) {
        int idx = tid + j * 256;              // 0..511
        int krow = idx >> 3, bcol = idx & 7;
        unsigned short h[8], l[8];
        #pragma unroll
        for (int i = 0; i < 8; ++i) {
            h[i] = ldsH[krow * 72 + bcol * 8 + i];
            l[i] = ldsL[krow * 72 + bcol * 8 + i];
        }
        const int gk = k0 + krow;             // global ri
        const int gcol = (b0 >> 3) + bcol;    // = kk*4 + q
        const int kk = gcol >> 2, q = gcol & 3;
        size_t o = ((size_t)(gk >> 4) * 8 + kk) * 64 + q * 16 + (gk & 15);
        PTh[o] = pack8(h);
        PTl[o] = pack8(l);
    }
}

// ---- MFMA s-GEMM + fused squash (round-7-proven maps; 512 thr, K/8 per wave).
// R15: A fragment-major. R16: B fragment-major too (1 segment per load).
// XCD-aware block->tile swizzle kept. Writes v fragment-major VT[mt][kk][lane]
// (hi/lo uint2 halves) for agree A; last iter writes outb.
__global__ __launch_bounds__(512) void sgemm_kernel(
    const uint4* __restrict__ Ah, const uint4* __restrict__ Al,
    const uint4* __restrict__ Bh, const uint4* __restrict__ Bl,
    uint2* __restrict__ vth, uint2* __restrict__ vtl,
    float* __restrict__ outb, int uniform, int last)
{
    __shared__ float comb[8][64][4];
    const int tid = threadIdx.x;
    const int wave = tid >> 6, lane = tid & 63;
    const int lm = lane & 15, q = lane >> 4;
    const int xcd = blockIdx.x & 7, s0 = blockIdx.x >> 3;
    const int c = (xcd & 1) * 5 + (s0 % 5);
    const int b0 = ((xcd >> 1) * 4 + (s0 / 5)) * 16;

    const uint4* Ahp = Ah + (size_t)(b0 >> 4) * 288 * 64 + lane;
    const uint4* Alp = Al + (size_t)(b0 >> 4) * 288 * 64 + lane;
    const uint4* Bhp = Bh + (size_t)c * 288 * 64 + lane;
    const uint4* Blp = Bl + (size_t)c * 288 * 64 + lane;

    v4f acc = {0.f, 0.f, 0.f, 0.f};
    const int kk0 = wave * 36;
    for (int kk = kk0; kk < kk0 + 36; ++kk) {
        bf16x8 ah = __builtin_bit_cast(bf16x8, Ahp[(size_t)kk * 64]);
        bf16x8 al = __builtin_bit_cast(bf16x8, Alp[(size_t)kk * 64]);
        bf16x8 bh = __builtin_bit_cast(bf16x8, Bhp[(size_t)kk * 64]);
        bf16x8 bl = __builtin_bit_cast(bf16x8, Blp[(size_t)kk * 64]);
        acc = __builtin_amdgcn_mfma_f32_16x16x32_bf16(ah, bh, acc, 0, 0, 0);
        acc = __builtin_amdgcn_mfma_f32_16x16x32_bf16(ah, bl, acc, 0, 0, 0);
        acc = __builtin_amdgcn_mfma_f32_16x16x32_bf16(al, bh, acc, 0, 0, 0);
    }
    #pragma unroll
    for (int r = 0; r < 4; ++r) comb[wave][lane][r] = acc[r];
    __syncthreads();
    if (wave == 0) {
        float s[4], sq[4];
        #pragma unroll
        for (int r = 0; r < 4; ++r) {
            s[r] = 0.f;
            #pragma unroll
            for (int w = 0; w < 8; ++w) s[r] += comb[w][lane][r];
            if (uniform) s[r] *= 0.1f;
            sq[r] = s[r] * s[r];
        }
        #pragma unroll
        for (int m = 1; m < 16; m <<= 1) {
            #pragma unroll
            for (int r = 0; r < 4; ++r) sq[r] += __shfl_xor(sq[r], m);
        }
        float v[4];
        #pragma unroll
        for (int r = 0; r < 4; ++r) {
            const float n = sq[r];
            v[r] = s[r] * sqrtf(n) / (1.0f + n);
        }
        if (!last) {
            unsigned short h[4], l[4];
            #pragma unroll
            for (int r = 0; r < 4; ++r) {
                h[r] = f2b(v[r]);
                l[r] = f2b(v[r] - b2f(h[r]));
            }
            // fragment-major VT: uint2 col jcol=(b0>>2)+q -> uint4 J=jcol>>1,
            // f=(c*8+(J>>2))*64+(J&3)*16+lm, o=2f+(jcol&1)
            const int jcol = (b0 >> 2) + q;
            const int J = jcol >> 1;
            const size_t f = ((size_t)c * 8 + (J >> 2)) * 64 + (J & 3) * 16 + lm;
            vth[f * 2 + (jcol & 1)] = pack4(h);
            vtl[f * 2 + (jcol & 1)] = pack4(l);
        } else {
            #pragma unroll
            for (int r = 0; r < 4; ++r)
                outb[((b0 + q * 4 + r) * 10 + c) * 16 + lm] = v[r];
        }
    }
}

// ---- agree: fused tgemm + reduce_bc. R16: all MFMA operand loads are
// fragment-major lane-contiguous (PT[tile][kk][lane], VT[mt][kk][lane]).
// Emits Bc hi/lo in W-matching fragment-major layout (write stays contiguous
// in t: o = (c*288+(r>>2))*512 + 128*(r&3) + t).
__global__ __launch_bounds__(256) void agree_kernel(
    const uint4* __restrict__ vth, const uint4* __restrict__ vtl,
    const uint4* __restrict__ PTh, const uint4* __restrict__ PTl,
    const float* __restrict__ Wf, float* __restrict__ b_log,
    unsigned short* __restrict__ Bh, unsigned short* __restrict__ Bl, int first)
{
    __shared__ float comb2[40][4][64];   // [mt*4+reg][wave][lane] - conflict-free
    __shared__ float G_lds[160][18];     // [cd][ri-local], pad 16->18
    __shared__ float part[4][10];
    __shared__ float cl[2][10];
    const int tid = threadIdx.x;
    const int wave = tid >> 6, lane = tid & 63;
    const int lm = lane & 15, q = lane >> 4;
    const int n0 = blockIdx.x * 16;

    const uint4* PThp = PTh + (size_t)blockIdx.x * 512 + lane;   // 8*64 per tile
    const uint4* PTlp = PTl + (size_t)blockIdx.x * 512 + lane;
    const uint4* vthp = vth + lane;
    const uint4* vtlp = vtl + lane;

    // ---- K-split tgemm: wave handles kk in {2*wave, 2*wave+1} ----
    v4f acc[10];
    #pragma unroll
    for (int mt = 0; mt < 10; ++mt) acc[mt] = (v4f){0.f, 0.f, 0.f, 0.f};
    #pragma unroll
    for (int kx = 0; kx < 2; ++kx) {
        const int kk = wave * 2 + kx;
        bf16x8 bh_ = __builtin_bit_cast(bf16x8, PThp[(size_t)kk * 64]);
        bf16x8 bl_ = __builtin_bit_cast(bf16x8, PTlp[(size_t)kk * 64]);
        #pragma unroll
        for (int mt = 0; mt < 10; ++mt) {
            bf16x8 ah = __builtin_bit_cast(bf16x8, vthp[(size_t)(mt * 8 + kk) * 64]);
            bf16x8 al = __builtin_bit_cast(bf16x8, vtlp[(size_t)(mt * 8 + kk) * 64]);
            acc[mt] = __builtin_amdgcn_mfma_f32_16x16x32_bf16(ah, bh_, acc[mt], 0, 0, 0);
            acc[mt] = __builtin_amdgcn_mfma_f32_16x16x32_bf16(ah, bl_, acc[mt], 0, 0, 0);
            acc[mt] = __builtin_amdgcn_mfma_f32_16x16x32_bf16(al, bh_, acc[mt], 0, 0, 0);
        }
    }
    #pragma unroll
    for (int mt = 0; mt < 10; ++mt)
        #pragma unroll
        for (int r = 0; r < 4; ++r)
            comb2[mt * 4 + r][wave][lane] = acc[mt][r];
    __syncthreads();
    // ---- sum wave partials -> G_lds. Wave w owns c40 = w*10 .. w*10+9 ----
    #pragma unroll
    for (int j = 0; j < 10; ++j) {
        const int c40 = wave * 10 + j;
        float s_ = comb2[c40][0][lane] + comb2[c40][1][lane]
                 + comb2[c40][2][lane] + comb2[c40][3][lane];
        const int mt = c40 >> 2, reg = c40 & 3;
        G_lds[mt * 16 + q * 4 + reg][lm] = s_;     // G[cd][ri = n0+lm]
    }
    __syncthreads();

    // ---- reduce_bc phase (proven logic; 128 threads per r-row) ----
    const int rl = tid >> 7;        // 0..1 -> which r this half-block owns
    const int t = tid & 127;        // d*8+i
    const int r = (n0 >> 3) + rl;
    const int wid2 = tid >> 6;      // 0..3

    float wv[10], a[10];
    #pragma unroll
    for (int c = 0; c < 10; ++c) {
        wv[c] = Wf[((size_t)r * 10 + c) * 128 + t];
        float g = G_lds[c * 16 + (t >> 3)][rl * 8 + (t & 7)];
        a[c] = wv[c] * g;
    }
    #pragma unroll
    for (int m = 1; m < 64; m <<= 1) {
        #pragma unroll
        for (int c = 0; c < 10; ++c) a[c] += __shfl_xor(a[c], m);
    }
    if (lane == 0) {
        #pragma unroll
        for (int c = 0; c < 10; ++c) part[wid2][c] = a[c];
    }
    __syncthreads();
    if (t < 10) {    // threads 0..9 (rl=0) and 128..137 (rl=1)
        float s_ = (part[rl * 2][t] + part[rl * 2 + 1][t]) * (1.0f / 256.0f);
        float bn = (first ? 0.f : b_log[r * 10 + t]) + s_;
        b_log[r * 10 + t] = bn;
        part[rl * 2][t] = bn;            // reuse as softmax scratch
    }
    __syncthreads();
    if (t < 10) {
        float mx = part[rl * 2][0];
        #pragma unroll
        for (int j = 1; j < 10; ++j) mx = fmaxf(mx, part[rl * 2][j]);
        float den = 0.f;
        #pragma unroll
        for (int j = 0; j < 10; ++j) den += __expf(part[rl * 2][j] - mx);
        cl[rl][t] = __expf(part[rl * 2][t] - mx) / den;
    }
    __syncthreads();
    #pragma unroll
    for (int c = 0; c < 10; ++c) {
        float x = cl[rl][c] * wv[c];
        unsigned short h = f2b(x);
        const size_t base = ((size_t)c * 288 + (r >> 2)) * 512 + 128 * (r & 3);
        Bh[base + t] = h;
        Bl[base + t] = f2b(x - b2f(h));
    }
}

extern "C" void kernel_launch(void* const* d_in, const int* in_sizes, int n_in,
                              void* d_out, int out_size, void* d_ws, size_t ws_size,
                              hipStream_t stream)
{
    const float4* P4 = (const float4*)d_in[0];
    const float4* W4 = (const float4*)d_in[1];
    char* wsb = (char*)d_ws;
    // BYTE offsets (audited, all 16B-aligned):
    float* b_log = (float*)(wsb + 0);              // 46080 B
    uint2* vth   = (uint2*)(wsb + 131072);         // 81920 B
    uint2* vtl   = (uint2*)(wsb + 262144);         // 81920 B
    uint4* PAh   = (uint4*)(wsb + 393216);         // 4718592 B (16*288*64*16)
    uint4* PAl   = (uint4*)(wsb + 5242880);        // 4718592 B
    uint4* PTh   = (uint4*)(wsb + 10485760);       // 4718592 B (576*8*64*16)
    uint4* PTl   = (uint4*)(wsb + 15728640);       // 4718592 B
    uint2* Wh    = (uint2*)(wsb + 20971520);       // 2949120 B (10*288*64*16)
    uint2* Wl    = (uint2*)(wsb + 25165824);       // 2949120 B
    unsigned short* Bh = (unsigned short*)(wsb + 29360128);  // 2949120 B
    unsigned short* Bl = (unsigned short*)(wsb + 33554432);  // 2949120 B
    float* outb  = (float*)d_out;
    const float* Wf = (const float*)W4;

    split_pw_kernel<<<2016, 256, 0, stream>>>(P4, PAh, PAl, PTh, PTl, W4, Wh, Wl);

    // iter 0: B = W, uniform c = 0.1 post-MFMA
    sgemm_kernel<<<160, 512, 0, stream>>>((const uint4*)PAh, (const uint4*)PAl,
                                          (const uint4*)Wh, (const uint4*)Wl,
                                          vth, vtl, outb, 1, 0);
    agree_kernel<<<576, 256, 0, stream>>>((const uint4*)vth, (const uint4*)vtl,
                                          PTh, PTl, Wf, b_log, Bh, Bl, 1);
    // iter 1
    sgemm_kernel<<<160, 512, 0, stream>>>((const uint4*)PAh, (const uint4*)PAl,
                                          (const uint4*)Bh, (const uint4*)Bl,
                                          vth, vtl, outb, 0, 0);
    agree_kernel<<<576, 256, 0, stream>>>((const uint4*)vth, (const uint4*)vtl,
                                          PTh, PTl, Wf, b_log, Bh, Bl, 0);
    // iter 2 -> d_out
    sgemm_kernel<<<160, 512, 0, stream>>>((const uint4*)PAh, (const uint4*)PAl,
                                          (const uint4*)Bh, (const uint4*)Bl,
                                          vth, vtl, outb, 0, 1);
}

// Round 9
// 135.522 us; speedup vs baseline: 1.3238x; 1.0073x over previous
//
#include <hip/hip_runtime.h>
#include <hip/hip_bf16.h>
#include <math.h>

// DigitCaps routing. PROVEN: P/W/out all FP32; MFMA hi/lo split path correct
// (round 7: PASS absmax 1.95e-3). Round 9: fused agree + merged split -> 179.
// R10 cooperative -> 449 REGR. R11 block-ksplit -> 200 REGR. R12 MLP -> 184
// NEUTRAL. R13 XCD swizzle -> 178 kept. R14 TLP -> 179 NEUTRAL.
// R15: fragment-major A -> 160.5 WIN (VMEM segment-issue bound confirmed).
// R16: fragment-major W/Bc/PT/VT (all MFMA loads 1-seg) -> 136.5 WIN.
// R17 (this): split_pw internal fixes, same mechanism family:
//   pass-A: float row-major LDS plane (pad 65) -> kills 8-way-conflicted
//           32x ds_read_u16 per thread (re-split is bit-identical);
//   pass-B: item remap so PT writes are lane-contiguous (8 seg -> 1 seg);
//   W-path: 2x float4/thread -> uint4 writes (grid 1440 -> 720).
//   P [256][9216] f32, W [1152][10][16][8] f32, out v [256][10][16] f32.

typedef __bf16 bf16x8 __attribute__((ext_vector_type(8)));
typedef float v4f __attribute__((ext_vector_type(4)));

__device__ __forceinline__ float b2f(unsigned short u) {
    return __uint_as_float(((unsigned)u) << 16);
}
__device__ __forceinline__ unsigned short f2b(float f) {   // RNE, finite only
    unsigned x = __float_as_uint(f);
    return (unsigned short)((x + 0x7FFFu + ((x >> 16) & 1u)) >> 16);
}
__device__ __forceinline__ void split4(float4 x, unsigned short* h, unsigned short* l) {
    const float* xf = (const float*)&x;
    #pragma unroll
    for (int i = 0; i < 4; ++i) {
        h[i] = f2b(xf[i]);
        l[i] = f2b(xf[i] - b2f(h[i]));
    }
}
__device__ __forceinline__ uint2 pack4(const unsigned short* s) {
    uint2 w;
    w.x = s[0] | ((unsigned)s[1] << 16);
    w.y = s[2] | ((unsigned)s[3] << 16);
    return w;
}
__device__ __forceinline__ uint4 pack8(const unsigned short* s) {
    uint4 w;
    w.x = s[0] | ((unsigned)s[1] << 16); w.y = s[2] | ((unsigned)s[3] << 16);
    w.z = s[4] | ((unsigned)s[5] << 16); w.w = s[6] | ((unsigned)s[7] << 16);
    return w;
}

// ---- merged split: blocks [0,576) split P; blocks [576,1296) split W.
// Emits (all fragment-major, lane-contiguous for their consumers):
//   PA[bt=16][kk=288][lane=64]   uint4 hi/lo  (sgemm A)
//   PT[tile=576][kk=8][lane=64]  uint4 hi/lo  (agree B)
//   WF[c=10][kk=288][lane=64]    uint2 pairs  (sgemm B, iter 0)
__global__ __launch_bounds__(256) void split_pw_kernel(
    const float4* __restrict__ P4, uint4* __restrict__ PAh, uint4* __restrict__ PAl,
    uint4* __restrict__ PTh, uint4* __restrict__ PTl,
    const float4* __restrict__ W4, uint2* __restrict__ Wh, uint2* __restrict__ Wl)
{
    __shared__ unsigned short ldsH[64 * 72];   // transposed [k][b] (pass B)
    __shared__ unsigned short ldsL[64 * 72];
    __shared__ float ldsF[64 * 65];            // row-major floats (pass A), pad 65
    const int tid = threadIdx.x;

    if (blockIdx.x >= 576) {   // ---- W path: fragment-major remap, 2 f4/thr ----
        const int t16 = (blockIdx.x - 576) * 256 + tid;    // 0..184319
        const int d = t16 & 15;
        const int rc = t16 >> 4;           // r*10 + c
        const int cc = rc % 10, r = rc / 10;
        unsigned short h0[4], l0[4], h1[4], l1[4];
        split4(W4[(size_t)t16 * 2], h0, l0);
        split4(W4[(size_t)t16 * 2 + 1], h1, l1);
        const size_t f = ((size_t)cc * 288 + (r >> 2)) * 64 + (r & 3) * 16 + d;
        uint2 a0 = pack4(h0), a1 = pack4(h1);
        uint2 b0_ = pack4(l0), b1 = pack4(l1);
        uint4 wh; wh.x = a0.x; wh.y = a0.y; wh.z = a1.x; wh.w = a1.y;
        uint4 wl; wl.x = b0_.x; wl.y = b0_.y; wl.z = b1.x; wl.w = b1.y;
        ((uint4*)Wh)[f] = wh;
        ((uint4*)Wl)[f] = wl;
        return;
    }

    // ---- P path: stage transposed hi/lo ushort planes + row-major floats ----
    const int b0 = (blockIdx.x & 3) * 64;
    const int k0 = (blockIdx.x >> 2) * 64;
    #pragma unroll
    for (int j = 0; j < 4; ++j) {
        int idx = tid + j * 256;              // 0..1023
        int row = idx >> 4, col4 = idx & 15;  // b-local, k/4-local
        int g = (b0 + row) * 2304 + (k0 >> 2) + col4;
        float4 x = P4[g];
        unsigned short h[4], l[4];
        split4(x, h, l);
        const float* xf = (const float*)&x;
        #pragma unroll
        for (int i = 0; i < 4; ++i) {
            ldsH[(col4 * 4 + i) * 72 + row] = h[i];   // [k-local][b-local]
            ldsL[(col4 * 4 + i) * 72 + row] = l[i];
            ldsF[row * 65 + col4 * 4 + i] = xf[i];    // [b-local][k-local]
        }
    }
    __syncthreads();
    // ---- pass A: fragment-major PA for sgemm. Reads 8 contiguous floats
    // (conflict-light, pad-65) and re-splits -> bit-identical to staging. ----
    #pragma unroll
    for (int j = 0; j < 2; ++j) {
        int idx = tid + j * 256;              // 0..511
        int lane = idx & 63, sub = idx >> 6;  // sub 0..7
        int bt = sub & 3, kkl = sub >> 2;     // 0..1
        int lm = lane & 15, q = lane >> 4;
        const float* fp = &ldsF[(bt * 16 + lm) * 65 + kkl * 32 + q * 8];
        unsigned short h[8], l[8];
        #pragma unroll
        for (int t = 0; t < 8; ++t) {
            float f = fp[t];
            h[t] = f2b(f);
            l[t] = f2b(f - b2f(h[t]));
        }
        size_t o = ((size_t)((blockIdx.x & 3) * 4 + bt) * 288
                    + ((blockIdx.x >> 2) * 2 + kkl)) * 64 + lane;
        PAh[o] = pack8(h);
        PAl[o] = pack8(l);
    }
    // ---- pass B: fragment-major PT for agree. Item remap (tl,kkl,q,rm) so
    // the global write is lane-contiguous (o = base + lane); same content. ----
    #pragma unroll
    for (int j = 0; j < 2; ++j) {
        int idx = tid + j * 256;              // 0..511
        const int tl = idx >> 7, kkl = (idx >> 6) & 1;
        const int lane = idx & 63, q = lane >> 4, rm = lane & 15;
        const int krow = tl * 16 + rm, bcol = kkl * 4 + q;
        unsigned short h[8], l[8];
        #pragma unroll
        for (int i = 0; i < 8; ++i) {
            h[i] = ldsH[krow * 72 + bcol * 8 + i];
            l[i] = ldsL[krow * 72 + bcol * 8 + i];
        }
        const int m = blockIdx.x & 3;
        const int tile = (k0 >> 4) + tl;
        size_t o = ((size_t)tile * 8 + 2 * m + kkl) * 64 + lane;
        PTh[o] = pack8(h);
        PTl[o] = pack8(l);
    }
}

// ---- MFMA s-GEMM + fused squash (round-7-proven maps; 512 thr, K/8 per wave).
// R15/R16: A and B fragment-major (1 segment per load). XCD swizzle kept.
// Writes v fragment-major VT[mt][kk][lane] for agree A; last iter -> outb.
__global__ __launch_bounds__(512) void sgemm_kernel(
    const uint4* __restrict__ Ah, const uint4* __restrict__ Al,
    const uint4* __restrict__ Bh, const uint4* __restrict__ Bl,
    uint2* __restrict__ vth, uint2* __restrict__ vtl,
    float* __restrict__ outb, int uniform, int last)
{
    __shared__ float comb[8][64][4];
    const int tid = threadIdx.x;
    const int wave = tid >> 6, lane = tid & 63;
    const int lm = lane & 15, q = lane >> 4;
    const int xcd = blockIdx.x & 7, s0 = blockIdx.x >> 3;
    const int c = (xcd & 1) * 5 + (s0 % 5);
    const int b0 = ((xcd >> 1) * 4 + (s0 / 5)) * 16;

    const uint4* Ahp = Ah + (size_t)(b0 >> 4) * 288 * 64 + lane;
    const uint4* Alp = Al + (size_t)(b0 >> 4) * 288 * 64 + lane;
    const uint4* Bhp = Bh + (size_t)c * 288 * 64 + lane;
    const uint4* Blp = Bl + (size_t)c * 288 * 64 + lane;

    v4f acc = {0.f, 0.f, 0.f, 0.f};
    const int kk0 = wave * 36;
    for (int kk = kk0; kk < kk0 + 36; ++kk) {
        bf16x8 ah = __builtin_bit_cast(bf16x8, Ahp[(size_t)kk * 64]);
        bf16x8 al = __builtin_bit_cast(bf16x8, Alp[(size_t)kk * 64]);
        bf16x8 bh = __builtin_bit_cast(bf16x8, Bhp[(size_t)kk * 64]);
        bf16x8 bl = __builtin_bit_cast(bf16x8, Blp[(size_t)kk * 64]);
        acc = __builtin_amdgcn_mfma_f32_16x16x32_bf16(ah, bh, acc, 0, 0, 0);
        acc = __builtin_amdgcn_mfma_f32_16x16x32_bf16(ah, bl, acc, 0, 0, 0);
        acc = __builtin_amdgcn_mfma_f32_16x16x32_bf16(al, bh, acc, 0, 0, 0);
    }
    #pragma unroll
    for (int r = 0; r < 4; ++r) comb[wave][lane][r] = acc[r];
    __syncthreads();
    if (wave == 0) {
        float s[4], sq[4];
        #pragma unroll
        for (int r = 0; r < 4; ++r) {
            s[r] = 0.f;
            #pragma unroll
            for (int w = 0; w < 8; ++w) s[r] += comb[w][lane][r];
            if (uniform) s[r] *= 0.1f;
            sq[r] = s[r] * s[r];
        }
        #pragma unroll
        for (int m = 1; m < 16; m <<= 1) {
            #pragma unroll
            for (int r = 0; r < 4; ++r) sq[r] += __shfl_xor(sq[r], m);
        }
        float v[4];
        #pragma unroll
        for (int r = 0; r < 4; ++r) {
            const float n = sq[r];
            v[r] = s[r] * sqrtf(n) / (1.0f + n);
        }
        if (!last) {
            unsigned short h[4], l[4];
            #pragma unroll
            for (int r = 0; r < 4; ++r) {
                h[r] = f2b(v[r]);
                l[r] = f2b(v[r] - b2f(h[r]));
            }
            const int jcol = (b0 >> 2) + q;
            const int J = jcol >> 1;
            const size_t f = ((size_t)c * 8 + (J >> 2)) * 64 + (J & 3) * 16 + lm;
            vth[f * 2 + (jcol & 1)] = pack4(h);
            vtl[f * 2 + (jcol & 1)] = pack4(l);
        } else {
            #pragma unroll
            for (int r = 0; r < 4; ++r)
                outb[((b0 + q * 4 + r) * 10 + c) * 16 + lm] = v[r];
        }
    }
}

// ---- agree: fused tgemm + reduce_bc. All MFMA operand loads fragment-major
// lane-contiguous (PT[tile][kk][lane], VT[mt][kk][lane]). Emits Bc hi/lo in
// the W-matching fragment-major layout (write contiguous in t).
__global__ __launch_bounds__(256) void agree_kernel(
    const uint4* __restrict__ vth, const uint4* __restrict__ vtl,
    const uint4* __restrict__ PTh, const uint4* __restrict__ PTl,
    const float* __restrict__ Wf, float* __restrict__ b_log,
    unsigned short* __restrict__ Bh, unsigned short* __restrict__ Bl, int first)
{
    __shared__ float comb2[40][4][64];   // [mt*4+reg][wave][lane] - conflict-free
    __shared__ float G_lds[160][18];     // [cd][ri-local], pad 16->18
    __shared__ float part[4][10];
    __shared__ float cl[2][10];
    const int tid = threadIdx.x;
    const int wave = tid >> 6, lane = tid & 63;
    const int lm = lane & 15, q = lane >> 4;
    const int n0 = blockIdx.x * 16;

    const uint4* PThp = PTh + (size_t)blockIdx.x * 512 + lane;   // 8*64 per tile
    const uint4* PTlp = PTl + (size_t)blockIdx.x * 512 + lane;
    const uint4* vthp = vth + lane;
    const uint4* vtlp = vtl + lane;

    // ---- K-split tgemm: wave handles kk in {2*wave, 2*wave+1} ----
    v4f acc[10];
    #pragma unroll
    for (int mt = 0; mt < 10; ++mt) acc[mt] = (v4f){0.f, 0.f, 0.f, 0.f};
    #pragma unroll
    for (int kx = 0; kx < 2; ++kx) {
        const int kk = wave * 2 + kx;
        bf16x8 bh_ = __builtin_bit_cast(bf16x8, PThp[(size_t)kk * 64]);
        bf16x8 bl_ = __builtin_bit_cast(bf16x8, PTlp[(size_t)kk * 64]);
        #pragma unroll
        for (int mt = 0; mt < 10; ++mt) {
            bf16x8 ah = __builtin_bit_cast(bf16x8, vthp[(size_t)(mt * 8 + kk) * 64]);
            bf16x8 al = __builtin_bit_cast(bf16x8, vtlp[(size_t)(mt * 8 + kk) * 64]);
            acc[mt] = __builtin_amdgcn_mfma_f32_16x16x32_bf16(ah, bh_, acc[mt], 0, 0, 0);
            acc[mt] = __builtin_amdgcn_mfma_f32_16x16x32_bf16(ah, bl_, acc[mt], 0, 0, 0);
            acc[mt] = __builtin_amdgcn_mfma_f32_16x16x32_bf16(al, bh_, acc[mt], 0, 0, 0);
        }
    }
    #pragma unroll
    for (int mt = 0; mt < 10; ++mt)
        #pragma unroll
        for (int r = 0; r < 4; ++r)
            comb2[mt * 4 + r][wave][lane] = acc[mt][r];
    __syncthreads();
    // ---- sum wave partials -> G_lds. Wave w owns c40 = w*10 .. w*10+9 ----
    #pragma unroll
    for (int j = 0; j < 10; ++j) {
        const int c40 = wave * 10 + j;
        float s_ = comb2[c40][0][lane] + comb2[c40][1][lane]
                 + comb2[c40][2][lane] + comb2[c40][3][lane];
        const int mt = c40 >> 2, reg = c40 & 3;
        G_lds[mt * 16 + q * 4 + reg][lm] = s_;     // G[cd][ri = n0+lm]
    }
    __syncthreads();

    // ---- reduce_bc phase (proven logic; 128 threads per r-row) ----
    const int rl = tid >> 7;        // 0..1 -> which r this half-block owns
    const int t = tid & 127;        // d*8+i
    const int r = (n0 >> 3) + rl;
    const int wid2 = tid >> 6;      // 0..3

    float wv[10], a[10];
    #pragma unroll
    for (int c = 0; c < 10; ++c) {
        wv[c] = Wf[((size_t)r * 10 + c) * 128 + t];
        float g = G_lds[c * 16 + (t >> 3)][rl * 8 + (t & 7)];
        a[c] = wv[c] * g;
    }
    #pragma unroll
    for (int m = 1; m < 64; m <<= 1) {
        #pragma unroll
        for (int c = 0; c < 10; ++c) a[c] += __shfl_xor(a[c], m);
    }
    if (lane == 0) {
        #pragma unroll
        for (int c = 0; c < 10; ++c) part[wid2][c] = a[c];
    }
    __syncthreads();
    if (t < 10) {    // threads 0..9 (rl=0) and 128..137 (rl=1)
        float s_ = (part[rl * 2][t] + part[rl * 2 + 1][t]) * (1.0f / 256.0f);
        float bn = (first ? 0.f : b_log[r * 10 + t]) + s_;
        b_log[r * 10 + t] = bn;
        part[rl * 2][t] = bn;            // reuse as softmax scratch
    }
    __syncthreads();
    if (t < 10) {
        float mx = part[rl * 2][0];
        #pragma unroll
        for (int j = 1; j < 10; ++j) mx = fmaxf(mx, part[rl * 2][j]);
        float den = 0.f;
        #pragma unroll
        for (int j = 0; j < 10; ++j) den += __expf(part[rl * 2][j] - mx);
        cl[rl][t] = __expf(part[rl * 2][t] - mx) / den;
    }
    __syncthreads();
    #pragma unroll
    for (int c = 0; c < 10; ++c) {
        float x = cl[rl][c] * wv[c];
        unsigned short h = f2b(x);
        const size_t base = ((size_t)c * 288 + (r >> 2)) * 512 + 128 * (r & 3);
        Bh[base + t] = h;
        Bl[base + t] = f2b(x - b2f(h));
    }
}

extern "C" void kernel_launch(void* const* d_in, const int* in_sizes, int n_in,
                              void* d_out, int out_size, void* d_ws, size_t ws_size,
                              hipStream_t stream)
{
    const float4* P4 = (const float4*)d_in[0];
    const float4* W4 = (const float4*)d_in[1];
    char* wsb = (char*)d_ws;
    // BYTE offsets (audited, all 16B-aligned):
    float* b_log = (float*)(wsb + 0);              // 46080 B
    uint2* vth   = (uint2*)(wsb + 131072);         // 81920 B
    uint2* vtl   = (uint2*)(wsb + 262144);         // 81920 B
    uint4* PAh   = (uint4*)(wsb + 393216);         // 4718592 B (16*288*64*16)
    uint4* PAl   = (uint4*)(wsb + 5242880);        // 4718592 B
    uint4* PTh   = (uint4*)(wsb + 10485760);       // 4718592 B (576*8*64*16)
    uint4* PTl   = (uint4*)(wsb + 15728640);       // 4718592 B
    uint2* Wh    = (uint2*)(wsb + 20971520);       // 2949120 B (10*288*64*16)
    uint2* Wl    = (uint2*)(wsb + 25165824);       // 2949120 B
    unsigned short* Bh = (unsigned short*)(wsb + 29360128);  // 2949120 B
    unsigned short* Bl = (unsigned short*)(wsb + 33554432);  // 2949120 B
    float* outb  = (float*)d_out;
    const float* Wf = (const float*)W4;

    split_pw_kernel<<<1296, 256, 0, stream>>>(P4, PAh, PAl, PTh, PTl, W4, Wh, Wl);

    // iter 0: B = W, uniform c = 0.1 post-MFMA
    sgemm_kernel<<<160, 512, 0, stream>>>((const uint4*)PAh, (const uint4*)PAl,
                                          (const uint4*)Wh, (const uint4*)Wl,
                                          vth, vtl, outb, 1, 0);
    agree_kernel<<<576, 256, 0, stream>>>((const uint4*)vth, (const uint4*)vtl,
                                          PTh, PTl, Wf, b_log, Bh, Bl, 1);
    // iter 1
    sgemm_kernel<<<160, 512, 0, stream>>>((const uint4*)PAh, (const uint4*)PAl,
                                          (const uint4*)Bh, (const uint4*)Bl,
                                          vth, vtl, outb, 0, 0);
    agree_kernel<<<576, 256, 0, stream>>>((const uint4*)vth, (const uint4*)vtl,
                                          PTh, PTl, Wf, b_log, Bh, Bl, 0);
    // iter 2 -> d_out
    sgemm_kernel<<<160, 512, 0, stream>>>((const uint4*)PAh, (const uint4*)PAl,
                                          (const uint4*)Bh, (const uint4*)Bl,
                                          vth, vtl, outb, 0, 1);
}